// Round 3
// baseline (423.611 us; speedup 1.0000x reference)
//
#include <hip/hip_runtime.h>

typedef _Float16 h16;
typedef __attribute__((ext_vector_type(8))) _Float16 h16x8;
typedef __attribute__((ext_vector_type(4))) float f32x4;
typedef unsigned int u32;

// ---------------- Kernel 1: A fp32 -> fp16 ----------------
__global__ __launch_bounds__(256) void cvtA_kernel(const float* __restrict__ A,
                                                   h16* __restrict__ Ah, int total8) {
  int stride = gridDim.x * blockDim.x;
  for (int i = blockIdx.x * blockDim.x + threadIdx.x; i < total8; i += stride) {
    const f32x4* p = (const f32x4*)(A + (size_t)i * 8);
    f32x4 v0 = p[0], v1 = p[1];
    h16x8 o;
    o[0] = (h16)v0[0]; o[1] = (h16)v0[1]; o[2] = (h16)v0[2]; o[3] = (h16)v0[3];
    o[4] = (h16)v1[0]; o[5] = (h16)v1[1]; o[6] = (h16)v1[2]; o[7] = (h16)v1[3];
    *(h16x8*)(Ah + (size_t)i * 8) = o;
  }
}

// ---------------- Kernel 2: dequant 2:4 int4 -> Wt [N][K] fp16 ----------------
// B [K/16][N] int32: 8 nibbles = compressed values kc = r*8+j (kc indexes K/2)
// meta [K/4][N] in [0,6): selects pair of positions within group of 4
// s [K/GS][N]: scale[kc] = s[kc*2/GS]
// pairs: 0:(0,1) 1:(0,2) 2:(0,3) 3:(1,2) 4:(1,3) 5:(2,3) -> enc p0|p1<<2 packed LUT
__global__ __launch_bounds__(256) void dequant_kernel(const int* __restrict__ Bq,
    const int* __restrict__ meta, const float* __restrict__ s,
    h16* __restrict__ Wt, int K, int N, int chunksPerGroup) {
  int n = blockIdx.x * 256 + threadIdx.x;       // column of W
  int chunk = blockIdx.y;                       // 32 dense k rows per chunk
  u32 w0 = (u32)Bq[(size_t)(chunk * 2) * N + n];
  u32 w1 = (u32)Bq[(size_t)(chunk * 2 + 1) * N + n];
  float sc = s[(size_t)(chunk / chunksPerGroup) * N + n];  // uniform per chunk (32 | GS)
  h16 out[32];
#pragma unroll
  for (int gi = 0; gi < 8; ++gi) {              // 8 groups of 4 dense k
    int g = chunk * 8 + gi;
    int mm = meta[(size_t)g * N + n];
    u32 w = (gi < 4) ? w0 : w1;
    int j0 = (2 * gi) & 7;                      // nibble index of value kc=2g
    float d0 = (float)((int)((w >> (4 * j0)) & 0xFu) - 8) * sc;
    float d1 = (float)((int)((w >> (4 * j0 + 4)) & 0xFu) - 8) * sc;
    u32 enc = (0xED9C84u >> (4 * mm)) & 0xFu;
    int p0 = (int)(enc & 3u), p1 = (int)(enc >> 2);
#pragma unroll
    for (int p = 0; p < 4; ++p) {
      float v = (p == p0) ? d0 : ((p == p1) ? d1 : 0.0f);
      out[gi * 4 + p] = (h16)v;
    }
  }
  h16* dst = Wt + (size_t)n * K + chunk * 32;
  *(h16x8*)(dst + 0)  = *(h16x8*)(out + 0);
  *(h16x8*)(dst + 8)  = *(h16x8*)(out + 8);
  *(h16x8*)(dst + 16) = *(h16x8*)(out + 16);
  *(h16x8*)(dst + 24) = *(h16x8*)(out + 24);
}

// ---------------- Kernel 3: GEMM C = A * Wt^T + bias ----------------
// A [M][K] f16 row-major, Wt [N][K] f16 row-major (i.e., W^T), C [M][N] f32.
// m97 structure: 128x128 tile, BK=32, 256 threads (4 waves, 2x2), 4x4 frags/wave,
// global_load_lds width 16, single LDS buffer, 2 barriers per K-step.
__global__ __launch_bounds__(256) void gemm_kernel(const h16* __restrict__ A,
    const h16* __restrict__ Wt, const float* __restrict__ bias,
    float* __restrict__ C, int M, int N, int K) {
  __shared__ alignas(16) h16 As[128 * 32];
  __shared__ alignas(16) h16 Bs[128 * 32];

  int nTilesN = N >> 7;
  int nwg = gridDim.x;
  int bid = blockIdx.x;
  // XCD-aware swizzle (nwg % 8 == 0 -> bijective)
  int wg = (bid & 7) * (nwg >> 3) + (bid >> 3);
  int tm = wg / nTilesN, tn = wg - tm * nTilesN;

  int t = threadIdx.x;
  int lane = t & 63, wid = t >> 6;
  int wr = wid >> 1, wc = wid & 1;

  const h16* Abase = A + (size_t)tm * 128 * K;
  const h16* Bbase = Wt + (size_t)tn * 128 * K;

  // staging: each wave fills 2 slots (1 KiB each) of A and of B.
  // slot covers 16 rows of the [128][32] tile; lane l -> row slot*16 + l/4, k (l%4)*8
  int slot0 = wid * 2, slot1 = wid * 2 + 1;
  int srow0 = slot0 * 16 + (lane >> 2);
  int srow1 = slot1 * 16 + (lane >> 2);
  int skq = (lane & 3) * 8;
  const h16* gA0 = Abase + (size_t)srow0 * K + skq;
  const h16* gA1 = Abase + (size_t)srow1 * K + skq;
  const h16* gB0 = Bbase + (size_t)srow0 * K + skq;
  const h16* gB1 = Bbase + (size_t)srow1 * K + skq;
  h16* lA0 = As + slot0 * 512 + lane * 8;
  h16* lA1 = As + slot1 * 512 + lane * 8;
  h16* lB0 = Bs + slot0 * 512 + lane * 8;
  h16* lB1 = Bs + slot1 * 512 + lane * 8;

  f32x4 acc[4][4] = {};

  // fragment read bases: A-frag row = wr*64 + m*16 + (lane&15), k = (lane>>4)*8
  const h16* ArdBase = As + (size_t)(wr * 64 + (lane & 15)) * 32 + (lane >> 4) * 8;
  const h16* BrdBase = Bs + (size_t)(wc * 64 + (lane & 15)) * 32 + (lane >> 4) * 8;

  for (int k0 = 0; k0 < K; k0 += 32) {
    __builtin_amdgcn_global_load_lds(
        (__attribute__((address_space(1))) void*)(gA0 + k0),
        (__attribute__((address_space(3))) void*)lA0, 16, 0, 0);
    __builtin_amdgcn_global_load_lds(
        (__attribute__((address_space(1))) void*)(gA1 + k0),
        (__attribute__((address_space(3))) void*)lA1, 16, 0, 0);
    __builtin_amdgcn_global_load_lds(
        (__attribute__((address_space(1))) void*)(gB0 + k0),
        (__attribute__((address_space(3))) void*)lB0, 16, 0, 0);
    __builtin_amdgcn_global_load_lds(
        (__attribute__((address_space(1))) void*)(gB1 + k0),
        (__attribute__((address_space(3))) void*)lB1, 16, 0, 0);
    __syncthreads();  // drains vmcnt before barrier (compiler-inserted)

    h16x8 af[4], bf[4];
#pragma unroll
    for (int m = 0; m < 4; ++m) af[m] = *(const h16x8*)(ArdBase + m * 16 * 32);
#pragma unroll
    for (int n = 0; n < 4; ++n) bf[n] = *(const h16x8*)(BrdBase + n * 16 * 32);
#pragma unroll
    for (int m = 0; m < 4; ++m)
#pragma unroll
      for (int n = 0; n < 4; ++n)
        acc[m][n] = __builtin_amdgcn_mfma_f32_16x16x32_f16(af[m], bf[n], acc[m][n], 0, 0, 0);
    __syncthreads();
  }

  // epilogue: D col = lane&15, row = (lane>>4)*4 + j  (verified mapping)
  int colBase = tn * 128 + wc * 64 + (lane & 15);
  int rowBase = tm * 128 + wr * 64 + (lane >> 4) * 4;
#pragma unroll
  for (int n = 0; n < 4; ++n) {
    float bv = bias[colBase + n * 16];
#pragma unroll
    for (int m = 0; m < 4; ++m) {
#pragma unroll
      for (int j = 0; j < 4; ++j) {
        C[(size_t)(rowBase + m * 16 + j) * N + colBase + n * 16] = acc[m][n][j] + bv;
      }
    }
  }
}

extern "C" void kernel_launch(void* const* d_in, const int* in_sizes, int n_in,
                              void* d_out, int out_size, void* d_ws, size_t ws_size,
                              hipStream_t stream) {
  const float* A = (const float*)d_in[0];
  const int* Bq = (const int*)d_in[1];
  const int* meta = (const int*)d_in[2];
  const float* s = (const float*)d_in[3];
  const float* bias = (const float*)d_in[4];
  float* C = (float*)d_out;

  // derive shapes: N from bias, K from B (= K/16 * N), M from A
  const int N = in_sizes[4];
  const int K = (int)(((long long)in_sizes[1] * 16) / N);
  const int M = (int)((long long)in_sizes[0] / K);
  const int sRows = (int)((long long)in_sizes[3] / N);       // K/GS
  const int chunksPerGroup = (K / sRows) / 32;               // GS/32

  h16* Ah = (h16*)d_ws;                       // M*K f16 = 64 MiB
  h16* Wt = Ah + (size_t)M * K;               // N*K f16 = 32 MiB (W^T, K-major)

  cvtA_kernel<<<2048, 256, 0, stream>>>(A, Ah, (M * K) / 8);

  dim3 dgrid(N / 256, K / 32);
  dequant_kernel<<<dgrid, 256, 0, stream>>>(Bq, meta, s, Wt, K, N, chunksPerGroup);

  int grid = (M / 128) * (N / 128);
  gemm_kernel<<<grid, 256, 0, stream>>>(Ah, Wt, bias, C, M, N, K);
}

// Round 4
// 317.944 us; speedup vs baseline: 1.3323x; 1.3323x over previous
//
#include <hip/hip_runtime.h>

typedef _Float16 h16;
typedef __attribute__((ext_vector_type(8))) _Float16 h16x8;
typedef __attribute__((ext_vector_type(4))) float f32x4;
typedef unsigned int u32;

#define BARRIER() __builtin_amdgcn_s_barrier()
#define SCHEDB()  __builtin_amdgcn_sched_barrier(0)

// ---------------- Kernel 1: A fp32 -> fp16 ----------------
__global__ __launch_bounds__(256) void cvtA_kernel(const float* __restrict__ A,
                                                   h16* __restrict__ Ah, int total8) {
  int stride = gridDim.x * blockDim.x;
  for (int i = blockIdx.x * blockDim.x + threadIdx.x; i < total8; i += stride) {
    const f32x4* p = (const f32x4*)(A + (size_t)i * 8);
    f32x4 v0 = p[0], v1 = p[1];
    h16x8 o;
    o[0] = (h16)v0[0]; o[1] = (h16)v0[1]; o[2] = (h16)v0[2]; o[3] = (h16)v0[3];
    o[4] = (h16)v1[0]; o[5] = (h16)v1[1]; o[6] = (h16)v1[2]; o[7] = (h16)v1[3];
    *(h16x8*)(Ah + (size_t)i * 8) = o;
  }
}

// ---------------- Kernel 2: dequant 2:4 int4 -> Wt [N][K] fp16 ----------------
__global__ __launch_bounds__(256) void dequant_kernel(const int* __restrict__ Bq,
    const int* __restrict__ meta, const float* __restrict__ s,
    h16* __restrict__ Wt, int K, int N, int chunksPerGroup) {
  int n = blockIdx.x * 256 + threadIdx.x;       // column of W
  int chunk = blockIdx.y;                       // 32 dense k rows per chunk
  u32 w0 = (u32)Bq[(size_t)(chunk * 2) * N + n];
  u32 w1 = (u32)Bq[(size_t)(chunk * 2 + 1) * N + n];
  float sc = s[(size_t)(chunk / chunksPerGroup) * N + n];
  h16 out[32];
#pragma unroll
  for (int gi = 0; gi < 8; ++gi) {
    int g = chunk * 8 + gi;
    int mm = meta[(size_t)g * N + n];
    u32 w = (gi < 4) ? w0 : w1;
    int j0 = (2 * gi) & 7;
    float d0 = (float)((int)((w >> (4 * j0)) & 0xFu) - 8) * sc;
    float d1 = (float)((int)((w >> (4 * j0 + 4)) & 0xFu) - 8) * sc;
    u32 enc = (0xED9C84u >> (4 * mm)) & 0xFu;
    int p0 = (int)(enc & 3u), p1 = (int)(enc >> 2);
#pragma unroll
    for (int p = 0; p < 4; ++p) {
      float v = (p == p0) ? d0 : ((p == p1) ? d1 : 0.0f);
      out[gi * 4 + p] = (h16)v;
    }
  }
  h16* dst = Wt + (size_t)n * K + chunk * 32;
  *(h16x8*)(dst + 0)  = *(h16x8*)(out + 0);
  *(h16x8*)(dst + 8)  = *(h16x8*)(out + 8);
  *(h16x8*)(dst + 16) = *(h16x8*)(out + 16);
  *(h16x8*)(dst + 24) = *(h16x8*)(out + 24);
}

// ---------------- Kernel 3: GEMM C = A * Wt^T + bias (deep pipeline) ----------
// 256x256 tile, BK=32, 512 threads (8 waves = 2M x 4N), per-wave 128x64 out.
// LDS: 4 rotating slots x (A 16K + B 16K) = 128 KiB. Prefetch distance 3.
// Counted vmcnt(8) per sub-tile (T4); XOR swizzle byte^=((row>>1)&3)<<4 (T2,
// applied via pre-swizzled global source, rule #21); setprio around MFMA (T5).
__global__ __launch_bounds__(512, 2) void gemm_kernel(const h16* __restrict__ A,
    const h16* __restrict__ Wt, const float* __restrict__ bias,
    float* __restrict__ C, int M, int N, int K) {
  __shared__ alignas(16) h16 As[4][256 * 32];
  __shared__ alignas(16) h16 Bs[4][256 * 32];

  const int nTilesN = N >> 8;
  const int nwg = gridDim.x;
  int bid = blockIdx.x;
  int wg = (bid & 7) * (nwg >> 3) + (bid >> 3);   // XCD swizzle (nwg%8==0)
  int tm = wg / nTilesN, tn = wg - tm * nTilesN;

  const int tid = threadIdx.x;
  const int lane = tid & 63, w = tid >> 6;
  const int wr = w >> 2, wc = w & 3;

  // ---- staging: thread covers LDS linear bytes tid*16 (+8192 for j=1) ----
  // linear byte lb -> (row=lb>>6, cb=lb&63); source col pre-swizzled by
  // S(row) = ((row>>1)&3)<<4. row = tid>>2 (+128 for j=1; bit7 doesn't touch
  // row bits 1-2, so same swizzle both halves).
  const int srow = tid >> 2;
  const int ssw = ((tid & 3) << 4) ^ (((tid >> 3) & 3) << 4);
  const char* gA = (const char*)(A + ((size_t)(tm * 256) + srow) * K) + ssw;
  const char* gB = (const char*)(Wt + ((size_t)(tn * 256) + srow) * K) + ssw;
  const size_t j1off = (size_t)128 * K * 2;      // +128 rows (bytes)
  const int ldsoff = tid * 16;

#define STAGE_A(t_) do { int sl_ = (t_) & 3;                                   \
    const char* src_ = gA + (size_t)(t_) * 64;                                 \
    char* dst_ = (char*)&As[sl_][0] + ldsoff;                                  \
    __builtin_amdgcn_global_load_lds(                                          \
        (const __attribute__((address_space(1))) void*)src_,                   \
        (__attribute__((address_space(3))) void*)dst_, 16, 0, 0);              \
    __builtin_amdgcn_global_load_lds(                                          \
        (const __attribute__((address_space(1))) void*)(src_ + j1off),         \
        (__attribute__((address_space(3))) void*)(dst_ + 8192), 16, 0, 0);     \
  } while (0)
#define STAGE_B(t_) do { int sl_ = (t_) & 3;                                   \
    const char* src_ = gB + (size_t)(t_) * 64;                                 \
    char* dst_ = (char*)&Bs[sl_][0] + ldsoff;                                  \
    __builtin_amdgcn_global_load_lds(                                          \
        (const __attribute__((address_space(1))) void*)src_,                   \
        (__attribute__((address_space(3))) void*)dst_, 16, 0, 0);              \
    __builtin_amdgcn_global_load_lds(                                          \
        (const __attribute__((address_space(1))) void*)(src_ + j1off),         \
        (__attribute__((address_space(3))) void*)(dst_ + 8192), 16, 0, 0);     \
  } while (0)

  // ---- fragment read addressing (swizzled) ----
  // A row = wr*128 + m*16 + (lane&15); col byte = ((lane>>4)<<4) ^ S(row);
  // S depends only on lane bits 1-2 -> constant per lane.
  const int cbR = ((lane >> 4) << 4) ^ (((lane >> 1) & 3) << 4);
  const int arow = wr * 128 + (lane & 15);
  const int brow = wc * 64 + (lane & 15);

  f32x4 acc[8][4] = {};

  const int NT = K >> 5;
  // prologue: stage sub-tiles 0,1,2 (12 loads); wait oldest 4 (tile 0) done.
  STAGE_A(0); STAGE_B(0);
  STAGE_A(1); STAGE_B(1);
  STAGE_A(2); STAGE_B(2);
  asm volatile("s_waitcnt vmcnt(8)" ::: "memory");
  SCHEDB();
  BARRIER();
  SCHEDB();

  for (int t = 0; t < NT; ++t) {
    const int slot = t & 3;
    const char* a_s = (const char*)&As[slot][0];
    const char* b_s = (const char*)&Bs[slot][0];
    h16x8 af[4], bf[4];

    // ================= phase A: rows [0,64) of wave block =================
#pragma unroll
    for (int m = 0; m < 4; ++m)
      af[m] = *(const h16x8*)(a_s + (size_t)(arow + m * 16) * 64 + cbR);
#pragma unroll
    for (int n = 0; n < 4; ++n)
      bf[n] = *(const h16x8*)(b_s + (size_t)(brow + n * 16) * 64 + cbR);
    if (t + 3 < NT) STAGE_A(t + 3);
    SCHEDB();
    BARRIER();
    asm volatile("s_waitcnt lgkmcnt(0)" ::: "memory");
    SCHEDB();
    __builtin_amdgcn_s_setprio(1);
#pragma unroll
    for (int m = 0; m < 4; ++m)
#pragma unroll
      for (int n = 0; n < 4; ++n)
        acc[m][n] = __builtin_amdgcn_mfma_f32_16x16x32_f16(af[m], bf[n], acc[m][n], 0, 0, 0);
    __builtin_amdgcn_s_setprio(0);
    SCHEDB();
    BARRIER();
    SCHEDB();

    // ================= phase B: rows [64,128) of wave block ===============
#pragma unroll
    for (int m = 0; m < 4; ++m)
      af[m] = *(const h16x8*)(a_s + (size_t)(arow + 64 + m * 16) * 64 + cbR);
    if (t + 3 < NT) STAGE_B(t + 3);
    SCHEDB();
    BARRIER();
    asm volatile("s_waitcnt lgkmcnt(0)" ::: "memory");
    SCHEDB();
    __builtin_amdgcn_s_setprio(1);
#pragma unroll
    for (int m = 0; m < 4; ++m)
#pragma unroll
      for (int n = 0; n < 4; ++n)
        acc[4 + m][n] = __builtin_amdgcn_mfma_f32_16x16x32_f16(af[m], bf[n], acc[4 + m][n], 0, 0, 0);
    __builtin_amdgcn_s_setprio(0);
    SCHEDB();
    // counted waits: steady vmcnt(8) = 2 sub-tiles in flight; exact tail drain.
    if (t + 3 < NT) {
      asm volatile("s_waitcnt vmcnt(8)" ::: "memory");
    } else if (t + 2 < NT) {
      asm volatile("s_waitcnt vmcnt(4)" ::: "memory");
    } else if (t + 1 < NT) {
      asm volatile("s_waitcnt vmcnt(0)" ::: "memory");
    }
    SCHEDB();
    BARRIER();
    SCHEDB();
  }

  // ---- epilogue: acc[m] <-> row offset m*16 (uniform), col = B row ----
  int colBase = tn * 256 + wc * 64 + (lane & 15);
  int rowBase = tm * 256 + wr * 128 + (lane >> 4) * 4;
#pragma unroll
  for (int n = 0; n < 4; ++n) {
    float bv = bias[colBase + n * 16];
#pragma unroll
    for (int m = 0; m < 8; ++m) {
#pragma unroll
      for (int j = 0; j < 4; ++j) {
        C[(size_t)(rowBase + m * 16 + j) * N + colBase + n * 16] = acc[m][n][j] + bv;
      }
    }
  }
#undef STAGE_A
#undef STAGE_B
}

extern "C" void kernel_launch(void* const* d_in, const int* in_sizes, int n_in,
                              void* d_out, int out_size, void* d_ws, size_t ws_size,
                              hipStream_t stream) {
  const float* A = (const float*)d_in[0];
  const int* Bq = (const int*)d_in[1];
  const int* meta = (const int*)d_in[2];
  const float* s = (const float*)d_in[3];
  const float* bias = (const float*)d_in[4];
  float* C = (float*)d_out;

  const int N = in_sizes[4];
  const int K = (int)(((long long)in_sizes[1] * 16) / N);
  const int M = (int)((long long)in_sizes[0] / K);
  const int sRows = (int)((long long)in_sizes[3] / N);       // K/GS
  const int chunksPerGroup = (K / sRows) / 32;               // GS/32

  h16* Ah = (h16*)d_ws;                       // M*K f16 = 64 MiB
  h16* Wt = Ah + (size_t)M * K;               // N*K f16 = 32 MiB (W^T, K-major)

  cvtA_kernel<<<2048, 256, 0, stream>>>(A, Ah, (M * K) / 8);

  dim3 dgrid(N / 256, K / 32);
  dequant_kernel<<<dgrid, 256, 0, stream>>>(Bq, meta, s, Wt, K, N, chunksPerGroup);

  int grid = (M / 256) * (N / 256);
  gemm_kernel<<<grid, 512, 0, stream>>>(Ah, Wt, bias, C, M, N, K);
}

// Round 5
// 295.032 us; speedup vs baseline: 1.4358x; 1.0777x over previous
//
#include <hip/hip_runtime.h>

typedef _Float16 h16;
typedef __attribute__((ext_vector_type(8))) _Float16 h16x8;
typedef __attribute__((ext_vector_type(4))) float f32x4;
typedef unsigned int u32;

#define BARRIER() __builtin_amdgcn_s_barrier()
#define SCHEDB()  __builtin_amdgcn_sched_barrier(0)

// ---------------- Kernel 1: A fp32 -> fp16 ----------------
__global__ __launch_bounds__(256) void cvtA_kernel(const float* __restrict__ A,
                                                   h16* __restrict__ Ah, int total8) {
  int stride = gridDim.x * blockDim.x;
  for (int i = blockIdx.x * blockDim.x + threadIdx.x; i < total8; i += stride) {
    const f32x4* p = (const f32x4*)(A + (size_t)i * 8);
    f32x4 v0 = p[0], v1 = p[1];
    h16x8 o;
    o[0] = (h16)v0[0]; o[1] = (h16)v0[1]; o[2] = (h16)v0[2]; o[3] = (h16)v0[3];
    o[4] = (h16)v1[0]; o[5] = (h16)v1[1]; o[6] = (h16)v1[2]; o[7] = (h16)v1[3];
    *(h16x8*)(Ah + (size_t)i * 8) = o;
  }
}

// ---------------- Kernel 2: dequant 2:4 int4 -> Wt [N][K] fp16 ----------------
__global__ __launch_bounds__(256) void dequant_kernel(const int* __restrict__ Bq,
    const int* __restrict__ meta, const float* __restrict__ s,
    h16* __restrict__ Wt, int K, int N, int chunksPerGroup) {
  int n = blockIdx.x * 256 + threadIdx.x;
  int chunk = blockIdx.y;
  u32 w0 = (u32)Bq[(size_t)(chunk * 2) * N + n];
  u32 w1 = (u32)Bq[(size_t)(chunk * 2 + 1) * N + n];
  float sc = s[(size_t)(chunk / chunksPerGroup) * N + n];
  h16 out[32];
#pragma unroll
  for (int gi = 0; gi < 8; ++gi) {
    int g = chunk * 8 + gi;
    int mm = meta[(size_t)g * N + n];
    u32 w = (gi < 4) ? w0 : w1;
    int j0 = (2 * gi) & 7;
    float d0 = (float)((int)((w >> (4 * j0)) & 0xFu) - 8) * sc;
    float d1 = (float)((int)((w >> (4 * j0 + 4)) & 0xFu) - 8) * sc;
    u32 enc = (0xED9C84u >> (4 * mm)) & 0xFu;
    int p0 = (int)(enc & 3u), p1 = (int)(enc >> 2);
#pragma unroll
    for (int p = 0; p < 4; ++p) {
      float v = (p == p0) ? d0 : ((p == p1) ? d1 : 0.0f);
      out[gi * 4 + p] = (h16)v;
    }
  }
  h16* dst = Wt + (size_t)n * K + chunk * 32;
  *(h16x8*)(dst + 0)  = *(h16x8*)(out + 0);
  *(h16x8*)(dst + 8)  = *(h16x8*)(out + 8);
  *(h16x8*)(dst + 16) = *(h16x8*)(out + 16);
  *(h16x8*)(dst + 24) = *(h16x8*)(out + 24);
}

// ---------------- Kernel 3: GEMM, m201-style 8-phase schedule ----------------
// 256x256 tile, K-tiles of 64, 512 threads (8 waves 2Mx4N), per-wave 128x64.
// LDS: A[2buf][2half][128][64] + B same = 128 KiB. 4 phases per K-tile:
//   P1: read A-h0(8)+B-h0(4), stage (T+1).A-h1 ; MFMA Q(0,0)
//   P2: read B-h1(4),         stage (T+2).A-h0 ; MFMA Q(0,1)
//   P3: read A-h1(8),         stage (T+2).B-h0 ; MFMA Q(1,1)
//   P4: (no reads),           stage (T+2).B-h1 ; MFMA Q(1,0); vmcnt(6)
// Halves: A by 64-row stripes (mh), B by 32-row stripes (nh), compacted in LDS.
// XOR swizzle: LDS 16B-slot ^= (row&7); applied via pre-swizzled global source.
__global__ __launch_bounds__(512, 2) void gemm_kernel(const h16* __restrict__ A,
    const h16* __restrict__ Wt, const float* __restrict__ bias,
    float* __restrict__ C, int M, int N, int K) {
  __shared__ alignas(16) h16 As[2 * 2 * 8192];
  __shared__ alignas(16) h16 Bs[2 * 2 * 8192];

  const int nTilesN = N >> 8;
  const int nwg = gridDim.x;
  int bid = blockIdx.x;
  int wg = (bid & 7) * (nwg >> 3) + (bid >> 3);   // XCD swizzle (nwg%8==0)
  int tm = wg / nTilesN, tn = wg - tm * nTilesN;

  const int tid = threadIdx.x;
  const int lane = tid & 63, w = tid >> 6;
  const int wr = w >> 2, wc = w & 3;

  // ---- staging addressing (pre-swizzled global source, linear LDS dest) ----
  const int i0 = tid >> 3;                         // row within 64-row chunk
  const int sigma = (tid & 7) ^ ((tid >> 3) & 7);  // source 16B-slot
  const h16* gA_t = A + ((size_t)(tm * 256) + i0) * K + sigma * 8;
  const int rB0 = ((i0 >> 5) << 6) + (i0 & 31);    // B stripe-compact row
  const h16* gB_t = Wt + ((size_t)(tn * 256) + rB0) * K + sigma * 8;
  const int tid8 = tid * 8;
  const size_t rowK128 = (size_t)128 * K;

#define GLOAD(SRC, DST) __builtin_amdgcn_global_load_lds(                      \
    (const __attribute__((address_space(1))) void*)(SRC),                      \
    (__attribute__((address_space(3))) void*)(DST), 16, 0, 0)

#define STAGE_A(T_, mh_) do {                                                  \
    const h16* s_ = gA_t + (size_t)((mh_) * 64) * K + (T_) * 64;               \
    h16* d_ = As + ((((T_) & 1) * 2 + (mh_)) * 8192) + tid8;                   \
    GLOAD(s_, d_); GLOAD(s_ + rowK128, d_ + 4096); } while (0)

#define STAGE_B(T_, nh_) do {                                                  \
    const h16* s_ = gB_t + (size_t)((nh_) * 32) * K + (T_) * 64;               \
    h16* d_ = Bs + ((((T_) & 1) * 2 + (nh_)) * 8192) + tid8;                   \
    GLOAD(s_, d_); GLOAD(s_ + rowK128, d_ + 4096); } while (0)

  // ---- fragment read offsets (h16 units), swizzled slot = (ks*4+l16)^l7 ----
  const int ln15 = lane & 15, l16 = lane >> 4, l7 = lane & 7;
  const int aRow = (wr * 64 + ln15) * 64;
  const int bRow = (wc * 32 + ln15) * 64;
  const int sl0 = ((0 + l16) ^ l7) * 8;
  const int sl1 = ((4 + l16) ^ l7) * 8;

  f32x4 acc[8][4] = {};
  const int NT = K >> 6;

  // prologue: 7 half-tiles (t0 complete + t1.Ah0/Bh0/Bh1); retire t0.
  STAGE_A(0, 0); STAGE_B(0, 0); STAGE_B(0, 1); STAGE_A(0, 1);
  STAGE_A(1, 0); STAGE_B(1, 0); STAGE_B(1, 1);
  asm volatile("s_waitcnt vmcnt(6)" ::: "memory");
  SCHEDB();
  BARRIER();
  SCHEDB();

  for (int T = 0; T < NT; ++T) {
    const int buf = T & 1;
    const h16* a0 = As + (buf * 2 + 0) * 8192;
    const h16* a1 = As + (buf * 2 + 1) * 8192;
    const h16* b0 = Bs + (buf * 2 + 0) * 8192;
    const h16* b1 = Bs + (buf * 2 + 1) * 8192;
    h16x8 af[4][2], bf0[2][2], bf1[2][2];

    // ================= P1: Q(0,0) =================
#pragma unroll
    for (int m = 0; m < 4; ++m) {
      af[m][0] = *(const h16x8*)(a0 + aRow + m * 1024 + sl0);
      af[m][1] = *(const h16x8*)(a0 + aRow + m * 1024 + sl1);
    }
#pragma unroll
    for (int n = 0; n < 2; ++n) {
      bf0[n][0] = *(const h16x8*)(b0 + bRow + n * 1024 + sl0);
      bf0[n][1] = *(const h16x8*)(b0 + bRow + n * 1024 + sl1);
    }
    if (T + 1 < NT) STAGE_A(T + 1, 1);
    asm volatile("s_waitcnt lgkmcnt(8)" ::: "memory");
    SCHEDB();
    BARRIER();
    asm volatile("s_waitcnt lgkmcnt(0)" ::: "memory");
    SCHEDB();
    __builtin_amdgcn_s_setprio(1);
#pragma unroll
    for (int m = 0; m < 4; ++m)
#pragma unroll
      for (int n = 0; n < 2; ++n) {
        acc[m][n] = __builtin_amdgcn_mfma_f32_16x16x32_f16(af[m][0], bf0[n][0], acc[m][n], 0, 0, 0);
        acc[m][n] = __builtin_amdgcn_mfma_f32_16x16x32_f16(af[m][1], bf0[n][1], acc[m][n], 0, 0, 0);
      }
    __builtin_amdgcn_s_setprio(0);
    SCHEDB();
    BARRIER();

    // ================= P2: Q(0,1) =================
#pragma unroll
    for (int n = 0; n < 2; ++n) {
      bf1[n][0] = *(const h16x8*)(b1 + bRow + n * 1024 + sl0);
      bf1[n][1] = *(const h16x8*)(b1 + bRow + n * 1024 + sl1);
    }
    if (T + 2 < NT) STAGE_A(T + 2, 0);
    SCHEDB();
    BARRIER();
    asm volatile("s_waitcnt lgkmcnt(0)" ::: "memory");
    SCHEDB();
    __builtin_amdgcn_s_setprio(1);
#pragma unroll
    for (int m = 0; m < 4; ++m)
#pragma unroll
      for (int n = 0; n < 2; ++n) {
        acc[m][2 + n] = __builtin_amdgcn_mfma_f32_16x16x32_f16(af[m][0], bf1[n][0], acc[m][2 + n], 0, 0, 0);
        acc[m][2 + n] = __builtin_amdgcn_mfma_f32_16x16x32_f16(af[m][1], bf1[n][1], acc[m][2 + n], 0, 0, 0);
      }
    __builtin_amdgcn_s_setprio(0);
    SCHEDB();
    BARRIER();

    // ================= P3: Q(1,1) =================
#pragma unroll
    for (int m = 0; m < 4; ++m) {
      af[m][0] = *(const h16x8*)(a1 + aRow + m * 1024 + sl0);
      af[m][1] = *(const h16x8*)(a1 + aRow + m * 1024 + sl1);
    }
    if (T + 2 < NT) STAGE_B(T + 2, 0);
    SCHEDB();
    BARRIER();
    asm volatile("s_waitcnt lgkmcnt(0)" ::: "memory");
    SCHEDB();
    __builtin_amdgcn_s_setprio(1);
#pragma unroll
    for (int m = 0; m < 4; ++m)
#pragma unroll
      for (int n = 0; n < 2; ++n) {
        acc[4 + m][2 + n] = __builtin_amdgcn_mfma_f32_16x16x32_f16(af[m][0], bf1[n][0], acc[4 + m][2 + n], 0, 0, 0);
        acc[4 + m][2 + n] = __builtin_amdgcn_mfma_f32_16x16x32_f16(af[m][1], bf1[n][1], acc[4 + m][2 + n], 0, 0, 0);
      }
    __builtin_amdgcn_s_setprio(0);
    SCHEDB();
    BARRIER();

    // ================= P4: Q(1,0) =================
    if (T + 2 < NT) STAGE_B(T + 2, 1);
    SCHEDB();
    BARRIER();
    SCHEDB();
    __builtin_amdgcn_s_setprio(1);
#pragma unroll
    for (int m = 0; m < 4; ++m)
#pragma unroll
      for (int n = 0; n < 2; ++n) {
        acc[4 + m][n] = __builtin_amdgcn_mfma_f32_16x16x32_f16(af[m][0], bf0[n][0], acc[4 + m][n], 0, 0, 0);
        acc[4 + m][n] = __builtin_amdgcn_mfma_f32_16x16x32_f16(af[m][1], bf0[n][1], acc[4 + m][n], 0, 0, 0);
      }
    __builtin_amdgcn_s_setprio(0);
    SCHEDB();
    if (T < NT - 2) {
      asm volatile("s_waitcnt vmcnt(6)" ::: "memory");
    } else if (T == NT - 2) {
      asm volatile("s_waitcnt vmcnt(0)" ::: "memory");
    }
    SCHEDB();
    BARRIER();
    SCHEDB();
  }

  // ---- epilogue ----
  int colBase = tn * 256 + wc * 64 + ln15;
  int rowBase = tm * 256 + wr * 128 + l16 * 4;
#pragma unroll
  for (int n = 0; n < 4; ++n) {
    float bv = bias[colBase + n * 16];
#pragma unroll
    for (int m = 0; m < 8; ++m) {
#pragma unroll
      for (int j = 0; j < 4; ++j) {
        C[(size_t)(rowBase + m * 16 + j) * N + colBase + n * 16] = acc[m][n][j] + bv;
      }
    }
  }
#undef STAGE_A
#undef STAGE_B
#undef GLOAD
}

extern "C" void kernel_launch(void* const* d_in, const int* in_sizes, int n_in,
                              void* d_out, int out_size, void* d_ws, size_t ws_size,
                              hipStream_t stream) {
  const float* A = (const float*)d_in[0];
  const int* Bq = (const int*)d_in[1];
  const int* meta = (const int*)d_in[2];
  const float* s = (const float*)d_in[3];
  const float* bias = (const float*)d_in[4];
  float* C = (float*)d_out;

  const int N = in_sizes[4];
  const int K = (int)(((long long)in_sizes[1] * 16) / N);
  const int M = (int)((long long)in_sizes[0] / K);
  const int sRows = (int)((long long)in_sizes[3] / N);       // K/GS
  const int chunksPerGroup = (K / sRows) / 32;               // GS/32

  h16* Ah = (h16*)d_ws;                       // M*K f16 = 64 MiB
  h16* Wt = Ah + (size_t)M * K;               // N*K f16 = 32 MiB (W^T, K-major)

  cvtA_kernel<<<2048, 256, 0, stream>>>(A, Ah, (M * K) / 8);

  dim3 dgrid(N / 256, K / 32);
  dequant_kernel<<<dgrid, 256, 0, stream>>>(Bq, meta, s, Wt, K, N, chunksPerGroup);

  int grid = (M / 256) * (N / 256);
  gemm_kernel<<<grid, 512, 0, stream>>>(Ah, Wt, bias, C, M, N, K);
}